// Round 6
// baseline (1094.652 us; speedup 1.0000x reference)
//
#include <hip/hip_runtime.h>
#include <hip/hip_bf16.h>
#include <cstdint>
#include <cstddef>

typedef __attribute__((ext_vector_type(8))) short bf16x8;
typedef __attribute__((ext_vector_type(4))) float f32x4;
typedef unsigned short u16;

#define SCALE_Q 0.17677669529663687f  // 1/sqrt(32)

__device__ __forceinline__ u16 f2bf(float f) {
  __hip_bfloat16 h = __float2bfloat16(f);
  union { __hip_bfloat16 h; u16 u; } cv; cv.h = h; return cv.u;
}

__device__ __forceinline__ void gload_lds16(const void* g, void* l) {
  __builtin_amdgcn_global_load_lds(
      (const __attribute__((address_space(1))) uint32_t*)g,
      (__attribute__((address_space(3))) uint32_t*)l, 16, 0, 0);
}

// ---------------- weight fp32 -> bf16 ----------------
__global__ void cvt_kernel(const float* __restrict__ s, u16* __restrict__ d, int n) {
  int i = blockIdx.x * 256 + threadIdx.x;
  if (i < n) d[i] = f2bf(s[i]);
}

// ---------------- LN1 + roll(-3,-3) + window partition -> bf16 win ----------------
// one wave per OUTPUT (window-order) token
__global__ __launch_bounds__(256) void ln1_kernel(const float* __restrict__ x,
    const float* __restrict__ w, const float* __restrict__ bia, u16* __restrict__ win) {
  int wid = threadIdx.x >> 6, l = threadIdx.x & 63;
  int tok = blockIdx.x * 4 + wid;              // < 100352
  int b_ = tok / 49, t = tok - b_ * 49;
  int bb = b_ >> 6, wdw = b_ & 63;
  int wh = wdw >> 3, ww = wdw & 7;
  int th = t / 7, tw = t - th * 7;
  int hh = wh * 7 + th + 3; if (hh >= 56) hh -= 56;   // un-roll source coord
  int wp = ww * 7 + tw + 3; if (wp >= 56) wp -= 56;
  const float* src = x + ((size_t)bb * 3136 + hh * 56 + wp) * 384;
  float v[6]; float s = 0.f, ss = 0.f;
#pragma unroll
  for (int q = 0; q < 6; ++q) { v[q] = src[l + 64 * q]; s += v[q]; ss += v[q] * v[q]; }
#pragma unroll
  for (int m = 1; m < 64; m <<= 1) { s += __shfl_xor(s, m); ss += __shfl_xor(ss, m); }
  float mean = s * (1.f / 384.f);
  float var = ss * (1.f / 384.f) - mean * mean;
  float rstd = rsqrtf(var + 1e-5f);
  u16* dst = win + (size_t)tok * 384;
#pragma unroll
  for (int q = 0; q < 6; ++q) {
    int ci = l + 64 * q;
    dst[ci] = f2bf((v[q] - mean) * rstd * w[ci] + bia[ci]);
  }
}

// ---------------- LN2 (no permutation) ----------------
__global__ __launch_bounds__(256) void ln2_kernel(const float* __restrict__ x,
    const float* __restrict__ w, const float* __restrict__ bia, u16* __restrict__ o) {
  int wid = threadIdx.x >> 6, l = threadIdx.x & 63;
  int tok = blockIdx.x * 4 + wid;
  const float* src = x + (size_t)tok * 384;
  float v[6]; float s = 0.f, ss = 0.f;
#pragma unroll
  for (int q = 0; q < 6; ++q) { v[q] = src[l + 64 * q]; s += v[q]; ss += v[q] * v[q]; }
#pragma unroll
  for (int m = 1; m < 64; m <<= 1) { s += __shfl_xor(s, m); ss += __shfl_xor(ss, m); }
  float mean = s * (1.f / 384.f);
  float var = ss * (1.f / 384.f) - mean * mean;
  float rstd = rsqrtf(var + 1e-5f);
  u16* dst = o + (size_t)tok * 384;
#pragma unroll
  for (int q = 0; q < 6; ++q) {
    int ci = l + 64 * q;
    dst[ci] = f2bf((v[q] - mean) * rstd * w[ci] + bia[ci]);
  }
}

// ---------------- GEMM: C = A(MxK,bf16) @ W(NxK,bf16)^T + bias, fused epilogues ----
// EPI 0: qkv scatter (+q scale)   1: proj + window-reverse/roll + shortcut -> f32
// EPI 2: fc1 + exact gelu -> bf16 3: fc2 + residual -> f32
template <int EPI>
__global__ __launch_bounds__(256) void gemm_bt(
    const u16* __restrict__ A, const u16* __restrict__ W,
    const float* __restrict__ bias, int K, int nbn,
    u16* __restrict__ outb, float* __restrict__ outf, const float* __restrict__ addsrc) {
  __shared__ u16 lsA[128 * 64];
  __shared__ u16 lsB[128 * 64];
  int bid = blockIdx.x;
  int bm = bid / nbn, bn = bid - bm * nbn;
  int m0 = bm * 128, n0 = bn * 128;
  int tid = threadIdx.x;
  int w = tid >> 6, l = tid & 63;
  int wr = w >> 1, wc = w & 1;
  int g = l >> 4, c = l & 15;
  int lr = l >> 3, lc8 = (l & 7) * 8;
  f32x4 acc[4][4] = {};
  for (int k0 = 0; k0 < K; k0 += 64) {
#pragma unroll
    for (int q = 0; q < 4; ++q) {
      int row = w * 32 + q * 8 + lr;
      gload_lds16(A + (size_t)(m0 + row) * K + k0 + lc8, &lsA[(w * 32 + q * 8) * 64]);
      gload_lds16(W + (size_t)(n0 + row) * K + k0 + lc8, &lsB[(w * 32 + q * 8) * 64]);
    }
    __syncthreads();
#pragma unroll
    for (int kk = 0; kk < 2; ++kk) {
      bf16x8 af[4], bfr[4];
#pragma unroll
      for (int i = 0; i < 4; ++i)
        af[i] = *(const bf16x8*)&lsA[(wr * 64 + i * 16 + c) * 64 + kk * 32 + g * 8];
#pragma unroll
      for (int j = 0; j < 4; ++j)
        bfr[j] = *(const bf16x8*)&lsB[(wc * 64 + j * 16 + c) * 64 + kk * 32 + g * 8];
#pragma unroll
      for (int i = 0; i < 4; ++i)
#pragma unroll
        for (int j = 0; j < 4; ++j)
          acc[i][j] = __builtin_amdgcn_mfma_f32_16x16x32_bf16(af[i], bfr[j], acc[i][j], 0, 0, 0);
    }
    __syncthreads();
  }
#pragma unroll
  for (int i = 0; i < 4; ++i) {
#pragma unroll
    for (int r = 0; r < 4; ++r) {
      int row = m0 + wr * 64 + i * 16 + 4 * g + r;
#pragma unroll
      for (int j = 0; j < 4; ++j) {
        int col = n0 + wc * 64 + j * 16 + c;
        float v = acc[i][j][r] + bias[col];
        if (EPI == 0) {
          int s = col / 384, rem = col - s * 384;
          int hd = rem >> 5, d = rem & 31;
          if (s == 0) v *= SCALE_Q;
          int b_ = row / 49, t = row - b_ * 49;
          outb[(((size_t)s * 2048 + b_) * 12 + hd) * 1568 + t * 32 + d] = f2bf(v);
        } else if (EPI == 1) {
          int b_ = row / 49, t = row - b_ * 49;
          int bb = b_ >> 6, wdw = b_ & 63;
          int wh = wdw >> 3, ww = wdw & 7;
          int th = t / 7, tw = t - th * 7;
          int hh = wh * 7 + th + 3; if (hh >= 56) hh -= 56;  // roll back (+3,+3)
          int wp = ww * 7 + tw + 3; if (wp >= 56) wp -= 56;
          size_t oi = ((size_t)bb * 3136 + hh * 56 + wp) * 384 + col;
          outf[oi] = v + addsrc[oi];
        } else if (EPI == 2) {
          float gg = 0.5f * v * (1.f + erff(v * 0.70710678118654752f));
          outb[(size_t)row * 768 + col] = f2bf(gg);
        } else {
          size_t oi = (size_t)row * 384 + col;
          outf[oi] = v + addsrc[oi];
        }
      }
    }
  }
}

// ---------------- attention: one wave per (window, head) ----------------
__global__ __launch_bounds__(256) void attn_kernel(const u16* __restrict__ qkv,
    u16* __restrict__ outb, const float* __restrict__ rpb) {
  __shared__ u16 lsP[4][64 * 72];   // P, padded stride 72 (bank-safe)
  __shared__ u16 lsVT[4][32 * 72];  // V^T, zero-padded cols 49..63
  int wid = threadIdx.x >> 6, l = threadIdx.x & 63;
  int pair = blockIdx.x * 4 + wid;               // < 24576
  int b_ = pair / 12, head = pair - b_ * 12;
  int g = l >> 4, c = l & 15;
  const size_t tstride = (size_t)2048 * 12 * 1568;
  const u16* qp = qkv + ((size_t)b_ * 12 + head) * 1568;
  const u16* kp = qp + tstride;
  const u16* vp = kp + tstride;

  // S = Q*scale @ K^T  (rows/cols padded 49->64, row-clamped loads)
  bf16x8 aq[4], bk[4];
#pragma unroll
  for (int i = 0; i < 4; ++i) {
    int row = i * 16 + c; if (row > 48) row = 48;
    aq[i] = *(const bf16x8*)&qp[row * 32 + g * 8];
  }
#pragma unroll
  for (int j = 0; j < 4; ++j) {
    int row = j * 16 + c; if (row > 48) row = 48;
    bk[j] = *(const bf16x8*)&kp[row * 32 + g * 8];
  }
  f32x4 s[4][4] = {};
#pragma unroll
  for (int i = 0; i < 4; ++i)
#pragma unroll
    for (int j = 0; j < 4; ++j)
      s[i][j] = __builtin_amdgcn_mfma_f32_16x16x32_bf16(aq[i], bk[j], s[i][j], 0, 0, 0);

  // stage V^T (zero-padded)
  u16* vt = lsVT[wid];
  for (int idx = l; idx < 32 * 72; idx += 64) vt[idx] = 0;
  for (int idx = l; idx < 49 * 32; idx += 64) {
    int t = idx >> 5, d = idx & 31;
    vt[d * 72 + t] = vp[idx];
  }

  // rel-bias + shift-mask + online row softmax (16-lane group reduce)
  int wdw = b_ & 63;
  int wh = wdw >> 3, ww = wdw & 7;
  int cd[4], cm[4], ridc[4]; bool cbad[4];
#pragma unroll
  for (int jn = 0; jn < 4; ++jn) {
    int col = jn * 16 + c; cbad[jn] = col > 48; if (col > 48) col = 48;
    int d7 = (col * 37) >> 8; int m7 = col - d7 * 7;
    cd[jn] = d7; cm[jn] = m7;
    int rh = (wh < 7) ? 0 : ((d7 < 4) ? 1 : 2);
    int rw = (ww < 7) ? 0 : ((m7 < 4) ? 1 : 2);
    ridc[jn] = rh * 3 + rw;
  }
  u16* pw = lsP[wid];
#pragma unroll
  for (int i = 0; i < 4; ++i) {
#pragma unroll
    for (int r = 0; r < 4; ++r) {
      int row = i * 16 + 4 * g + r;
      int rowc = row > 48 ? 48 : row;
      int rd = (rowc * 37) >> 8; int rm = rowc - rd * 7;
      int rh = (wh < 7) ? 0 : ((rd < 4) ? 1 : 2);
      int rw = (ww < 7) ? 0 : ((rm < 4) ? 1 : 2);
      int ridr = rh * 3 + rw;
      float vj[4]; float mx = -3.0e38f;
#pragma unroll
      for (int jn = 0; jn < 4; ++jn) {
        int idx = (rd - cd[jn] + 6) * 13 + (rm - cm[jn] + 6);
        float v = s[i][jn][r] + rpb[idx * 12 + head];
        if (ridr != ridc[jn]) v -= 100.f;
        if (cbad[jn]) v = -1e30f;
        vj[jn] = v; mx = fmaxf(mx, v);
      }
#pragma unroll
      for (int m = 1; m < 16; m <<= 1) mx = fmaxf(mx, __shfl_xor(mx, m));
      float sm = 0.f;
#pragma unroll
      for (int jn = 0; jn < 4; ++jn) { vj[jn] = __expf(vj[jn] - mx); sm += vj[jn]; }
#pragma unroll
      for (int m = 1; m < 16; m <<= 1) sm += __shfl_xor(sm, m);
      float rinv = 1.f / sm;
#pragma unroll
      for (int jn = 0; jn < 4; ++jn) pw[row * 72 + jn * 16 + c] = f2bf(vj[jn] * rinv);
    }
  }

  // O = P @ V
  f32x4 o[4][2] = {};
#pragma unroll
  for (int kk = 0; kk < 2; ++kk) {
    bf16x8 vb[2];
#pragma unroll
    for (int n = 0; n < 2; ++n)
      vb[n] = *(const bf16x8*)&vt[(n * 16 + c) * 72 + kk * 32 + g * 8];
#pragma unroll
    for (int i = 0; i < 4; ++i) {
      bf16x8 pa = *(const bf16x8*)&pw[(i * 16 + c) * 72 + kk * 32 + g * 8];
#pragma unroll
      for (int n = 0; n < 2; ++n)
        o[i][n] = __builtin_amdgcn_mfma_f32_16x16x32_bf16(pa, vb[n], o[i][n], 0, 0, 0);
    }
  }
#pragma unroll
  for (int i = 0; i < 4; ++i) {
#pragma unroll
    for (int r = 0; r < 4; ++r) {
      int row = i * 16 + 4 * g + r;
      if (row < 49) {
#pragma unroll
        for (int n = 0; n < 2; ++n)
          outb[((size_t)b_ * 49 + row) * 384 + head * 32 + n * 16 + c] = f2bf(o[i][n][r]);
      }
    }
  }
}

// ---------------- launcher ----------------
// ws layout (bytes):
//   wq 0 (884736) | wp 884736 (294912) | w1 1179648 (589824) | w2 1769472 (589824)
//   win/attnout 2359296 (77070336) | qkv 79429632 (231211008) [xm reuses 79429632,
//   h at 156499968 (154140672)] -> total 310640640 (~296 MB). x2 buffer == d_out.
extern "C" void kernel_launch(void* const* d_in, const int* in_sizes, int n_in,
                              void* d_out, int out_size, void* d_ws, size_t ws_size,
                              hipStream_t stream) {
  const float* x    = (const float*)d_in[0];
  const float* n1w  = (const float*)d_in[1];
  const float* n1b  = (const float*)d_in[2];
  const float* qkvw = (const float*)d_in[3];
  const float* qkvb = (const float*)d_in[4];
  const float* rpb  = (const float*)d_in[5];
  const float* pjw  = (const float*)d_in[6];
  const float* pjb  = (const float*)d_in[7];
  const float* n2w  = (const float*)d_in[8];
  const float* n2b  = (const float*)d_in[9];
  const float* f1w  = (const float*)d_in[10];
  const float* f1b  = (const float*)d_in[11];
  const float* f2w  = (const float*)d_in[12];
  const float* f2b  = (const float*)d_in[13];
  float* out = (float*)d_out;
  uint8_t* ws = (uint8_t*)d_ws;
  u16* wq  = (u16*)(ws + 0);
  u16* wp  = (u16*)(ws + 884736);
  u16* w1  = (u16*)(ws + 1179648);
  u16* w2  = (u16*)(ws + 1769472);
  u16* win = (u16*)(ws + 2359296);
  u16* qkv = (u16*)(ws + 79429632);
  u16* xm  = qkv;
  u16* hb  = (u16*)(ws + 156499968);

  cvt_kernel<<<dim3(1728), dim3(256), 0, stream>>>(qkvw, wq, 442368);
  cvt_kernel<<<dim3(576),  dim3(256), 0, stream>>>(pjw,  wp, 147456);
  cvt_kernel<<<dim3(1152), dim3(256), 0, stream>>>(f1w,  w1, 294912);
  cvt_kernel<<<dim3(1152), dim3(256), 0, stream>>>(f2w,  w2, 294912);

  ln1_kernel<<<dim3(25088), dim3(256), 0, stream>>>(x, n1w, n1b, win);

  gemm_bt<0><<<dim3(784 * 9), dim3(256), 0, stream>>>(win, wq, qkvb, 384, 9,
                                                      qkv, (float*)nullptr, (const float*)nullptr);
  attn_kernel<<<dim3(6144), dim3(256), 0, stream>>>(qkv, win, rpb);

  gemm_bt<1><<<dim3(784 * 3), dim3(256), 0, stream>>>(win, wp, pjb, 384, 3,
                                                      (u16*)nullptr, out, x);
  ln2_kernel<<<dim3(25088), dim3(256), 0, stream>>>(out, n2w, n2b, xm);

  gemm_bt<2><<<dim3(784 * 6), dim3(256), 0, stream>>>(xm, w1, f1b, 384, 6,
                                                      hb, (float*)nullptr, (const float*)nullptr);
  gemm_bt<3><<<dim3(784 * 3), dim3(256), 0, stream>>>(hb, w2, f2b, 768, 3,
                                                      (u16*)nullptr, out, out);
}